// Round 16
// baseline (195.058 us; speedup 1.0000x reference)
//
#include <hip/hip_runtime.h>
#include <stdint.h>

#define DIMSZ 2048
#define NH 16
#define NKV 4
#define HD 128
#define BATCH 2
#define SEQ 2048
#define MROWS (BATCH*SEQ)          // 4096
#define NQKV (NH*HD + 2*NKV*HD)    // 3072

typedef unsigned short u16;
typedef float f32x4 __attribute__((ext_vector_type(4)));
typedef short short8 __attribute__((ext_vector_type(8)));
typedef __bf16 bf16x8 __attribute__((ext_vector_type(8)));
typedef unsigned short u16x4 __attribute__((ext_vector_type(4)));
typedef unsigned short u16x8 __attribute__((ext_vector_type(8)));

__device__ __forceinline__ u16 f2bf(float f) {
  __bf16 h = (__bf16)f;           // native RNE convert
  return __builtin_bit_cast(u16, h);
}

__device__ __forceinline__ float bf2f(u16 h) {
  union { uint32_t u; float f; } v; v.u = ((uint32_t)h) << 16; return v.f;
}

__device__ __forceinline__ void async16(void* lds, const void* g) {
  __builtin_amdgcn_global_load_lds(
      (const __attribute__((address_space(1))) void*)(g),
      (__attribute__((address_space(3))) void*)(lds), 16, 0, 0);
}

__device__ __forceinline__ bf16x8 load_frag(const u16* p) {
  short8 v = *reinterpret_cast<const short8*>(p);
  return __builtin_bit_cast(bf16x8, v);
}

// ------------- prep: x cast + merged transpose-cast of all 4 weights -------------
__global__ __launch_bounds__(256) void prep_kernel(const float* __restrict__ x,
                                                   const float* __restrict__ wq,
                                                   const float* __restrict__ wk,
                                                   const float* __restrict__ wv,
                                                   const float* __restrict__ wo,
                                                   u16* __restrict__ xb,
                                                   u16* __restrict__ wtqkv,
                                                   u16* __restrict__ wto) {
  __shared__ float tb[64][65];
  int y = blockIdx.y;
  if (y >= 80) {                 // ---- x cast branch ----
    int id = (y - 80) * 32 + blockIdx.x;            // 0..8191
    int i = (id * 256 + (int)threadIdx.x) * 4;
    float4 v = *reinterpret_cast<const float4*>(x + i);
    u16x4 o;
    o.x = f2bf(v.x); o.y = f2bf(v.y); o.z = f2bf(v.z); o.w = f2bf(v.w);
    *reinterpret_cast<u16x4*>(xb + i) = o;
    return;
  }
  const float* src; int srcN; u16* dst; int nbase;
  if (y < 32)      { src = wq; srcN = 2048; dst = wtqkv;                        nbase = y * 64; }
  else if (y < 40) { src = wk; srcN = 512;  dst = wtqkv + (size_t)2048 * 2048;  nbase = (y - 32) * 64; }
  else if (y < 48) { src = wv; srcN = 512;  dst = wtqkv + (size_t)2560 * 2048;  nbase = (y - 40) * 64; }
  else             { src = wo; srcN = 2048; dst = wto;                          nbase = (y - 48) * 64; }
  int k0 = blockIdx.x * 64;
  int t = threadIdx.x;
  int lr = t >> 4, lc = (t & 15) * 4;
#pragma unroll
  for (int i = 0; i < 4; ++i) {
    int row = lr + i * 16;
    float4 v = *reinterpret_cast<const float4*>(&src[(size_t)(k0 + row) * srcN + nbase + lc]);
    tb[row][lc] = v.x; tb[row][lc + 1] = v.y; tb[row][lc + 2] = v.z; tb[row][lc + 3] = v.w;
  }
  __syncthreads();
  int n = t >> 3, kg = (t & 7) * 8;
#pragma unroll
  for (int i = 0; i < 2; ++i) {
    int nn = n + i * 32;
    u16x8 o;
#pragma unroll
    for (int j = 0; j < 8; ++j) o[j] = f2bf(tb[kg + j][nn]);
    *reinterpret_cast<u16x8*>(&dst[(size_t)(nbase + nn) * 2048 + k0 + kg]) = o;
  }
}

// ---------------- 8-phase-style 256x256 GEMM (gemm1) ----------------
#define COMPUTE_PAIR(q)                                                              \
  {                                                                                  \
    bf16x8 af[2][2];                                                                 \
    _Pragma("unroll")                                                                \
    for (int m2 = 0; m2 < 2; ++m2)                                                   \
      _Pragma("unroll")                                                              \
      for (int kk = 0; kk < 2; ++kk)                                                 \
        af[m2][kk] = load_frag(&lds[buf][0][wm * 8192 +                              \
            (((q) * 2 + m2) * 16 + l16) * 64 + ((kk * 4 + lg) ^ (l16 & 7)) * 8]);    \
    __builtin_amdgcn_s_setprio(1);                                                   \
    _Pragma("unroll")                                                                \
    for (int m2 = 0; m2 < 2; ++m2)                                                   \
      _Pragma("unroll")                                                              \
      for (int ni = 0; ni < 4; ++ni)                                                 \
        _Pragma("unroll")                                                            \
        for (int kk = 0; kk < 2; ++kk)                                               \
          acc[(q) * 2 + m2][ni] = __builtin_amdgcn_mfma_f32_16x16x32_bf16(           \
              af[m2][kk], bper[ni][kk], acc[(q) * 2 + m2][ni], 0, 0, 0);             \
    __builtin_amdgcn_s_setprio(0);                                                   \
  }

template <bool BF16OUT>
__global__ __launch_bounds__(512, 2) void gemm8p_kernel(const u16* __restrict__ A,
                                                        const u16* __restrict__ BT,
                                                        void* __restrict__ Cp,
                                                        int M, int N, int K, int gx) {
  __shared__ u16 lds[2][2][16384];   // [buf][A/B][256 rows x 64] = 128 KiB
  const int tid = threadIdx.x;
  const int wave = tid >> 6, lane = tid & 63;
  const int l16 = lane & 15, lg = lane >> 4;
  const int wm = wave >> 2, wn = wave & 3;
  const int rloc = lane >> 3;
  const int sOff = ((lane & 7) ^ rloc) * 8;
  const int nwg = gridDim.x;
  const int swz = (blockIdx.x & 7) * (nwg >> 3) + (blockIdx.x >> 3);
  const int bm = (swz / gx) * 256, bn = (swz % gx) * 256;

  f32x4 acc[8][4] = {};

  auto stage = [&](int dstbuf, int x, int h, const u16* xp, int xr0, int kk0) {
#pragma unroll
    for (int j = 0; j < 2; ++j) {
      int c = j * 8 + wave;   // 0..15, 1KB chunk = 8 rows
      async16(&lds[dstbuf][x][h * 8192 + c * 512],
              xp + (size_t)(xr0 + h * 128 + c * 8 + rloc) * K + kk0 + sOff);
    }
  };

  stage(0, 0, 0, A, bm, 0);
  stage(0, 0, 1, A, bm, 0);
  stage(0, 1, 0, BT, bn, 0);
  stage(0, 1, 1, BT, bn, 0);

  const int NT = K >> 6;
  for (int kt = 0; kt < NT; ++kt) {
    const int buf = kt & 1, nbuf = buf ^ 1;
    const int k0n = (kt + 1) << 6;
    const bool pf = (kt + 1 < NT);
    bf16x8 bper[4][2];

    if (pf) {
      stage(nbuf, 0, 0, A, bm, k0n);
      asm volatile("s_waitcnt vmcnt(2)" ::: "memory");
    } else {
      asm volatile("s_waitcnt vmcnt(0)" ::: "memory");
    }
    __builtin_amdgcn_s_barrier();
    __builtin_amdgcn_sched_barrier(0);
#pragma unroll
    for (int ni = 0; ni < 4; ++ni)
#pragma unroll
      for (int kk = 0; kk < 2; ++kk)
        bper[ni][kk] = load_frag(&lds[buf][1][(wn >> 1) * 8192 +
            ((wn & 1) * 64 + ni * 16 + l16) * 64 + ((kk * 4 + lg) ^ (l16 & 7)) * 8]);
    COMPUTE_PAIR(0)
    if (pf) stage(nbuf, 0, 1, A, bm, k0n);
    __builtin_amdgcn_s_barrier();
    __builtin_amdgcn_sched_barrier(0);
    COMPUTE_PAIR(1)
    if (pf) stage(nbuf, 1, 0, BT, bn, k0n);
    __builtin_amdgcn_s_barrier();
    __builtin_amdgcn_sched_barrier(0);
    COMPUTE_PAIR(2)
    if (pf) stage(nbuf, 1, 1, BT, bn, k0n);
    __builtin_amdgcn_s_barrier();
    __builtin_amdgcn_sched_barrier(0);
    COMPUTE_PAIR(3)
    __builtin_amdgcn_s_barrier();
  }

#pragma unroll
  for (int mi = 0; mi < 8; ++mi)
#pragma unroll
    for (int ni = 0; ni < 4; ++ni)
#pragma unroll
      for (int r = 0; r < 4; ++r) {
        size_t idx = (size_t)(bm + wm * 128 + mi * 16 + lg * 4 + r) * N +
                     bn + wn * 64 + ni * 16 + l16;
        if (BF16OUT) ((u16*)Cp)[idx] = f2bf(acc[mi][ni][r]);
        else         ((float*)Cp)[idx] = acc[mi][ni][r];
      }
}

// ---------------- 8-phase-style 256x128 GEMM (gemm2, fp32 out) ----------------
#define COMPUTE_MB(q)                                                                \
  {                                                                                  \
    bf16x8 af[2];                                                                    \
    _Pragma("unroll")                                                                \
    for (int kk = 0; kk < 2; ++kk)                                                   \
      af[kk] = load_frag(&lds2[buf][(wm * 64 + (q) * 16 + l16) * 64 +                \
                                    ((kk * 4 + lg) ^ (l16 & 7)) * 8]);               \
    __builtin_amdgcn_s_setprio(1);                                                   \
    _Pragma("unroll")                                                                \
    for (int ni = 0; ni < 4; ++ni)                                                   \
      _Pragma("unroll")                                                              \
      for (int kk = 0; kk < 2; ++kk)                                                 \
        acc[(q)][ni] = __builtin_amdgcn_mfma_f32_16x16x32_bf16(                      \
            af[kk], bper[ni][kk], acc[(q)][ni], 0, 0, 0);                            \
    __builtin_amdgcn_s_setprio(0);                                                   \
  }

__global__ __launch_bounds__(512, 2) void gemm8p_n128_kernel(const u16* __restrict__ A,
                                                             const u16* __restrict__ BT,
                                                             float* __restrict__ C,
                                                             int M, int N, int K, int gx) {
  __shared__ u16 lds2[2][24576];   // [buf][A 256x64 | B 128x64] = 96 KiB
  const int tid = threadIdx.x;
  const int wave = tid >> 6, lane = tid & 63;
  const int l16 = lane & 15, lg = lane >> 4;
  const int wm = wave >> 1, wn = wave & 1;
  const int rloc = lane >> 3;
  const int sOff = ((lane & 7) ^ rloc) * 8;
  const int nwg = gridDim.x;
  const int swz = (blockIdx.x & 7) * (nwg >> 3) + (blockIdx.x >> 3);
  const int bm = (swz / gx) * 256, bn = (swz % gx) * 128;

  f32x4 acc[4][4] = {};

  auto stageA = [&](int dstbuf, int h, int kk0) {
#pragma unroll
    for (int j = 0; j < 2; ++j) {
      int c = j * 8 + wave;
      async16(&lds2[dstbuf][h * 8192 + c * 512],
              A + (size_t)(bm + h * 128 + c * 8 + rloc) * K + kk0 + sOff);
    }
  };
  auto stageB = [&](int dstbuf, int kk0) {
#pragma unroll
    for (int j = 0; j < 2; ++j) {
      int c = j * 8 + wave;
      async16(&lds2[dstbuf][16384 + c * 512],
              BT + (size_t)(bn + c * 8 + rloc) * K + kk0 + sOff);
    }
  };

  stageA(0, 0, 0);
  stageA(0, 1, 0);
  stageB(0, 0);

  const int NT = K >> 6;
  for (int kt = 0; kt < NT; ++kt) {
    const int buf = kt & 1, nbuf = buf ^ 1;
    const int k0n = (kt + 1) << 6;
    const bool pf = (kt + 1 < NT);
    bf16x8 bper[4][2];

    if (pf) {
      stageA(nbuf, 0, k0n);
      asm volatile("s_waitcnt vmcnt(2)" ::: "memory");
    } else {
      asm volatile("s_waitcnt vmcnt(0)" ::: "memory");
    }
    __builtin_amdgcn_s_barrier();
    __builtin_amdgcn_sched_barrier(0);
#pragma unroll
    for (int ni = 0; ni < 4; ++ni)
#pragma unroll
      for (int kk = 0; kk < 2; ++kk)
        bper[ni][kk] = load_frag(&lds2[buf][16384 +
            (wn * 64 + ni * 16 + l16) * 64 + ((kk * 4 + lg) ^ (l16 & 7)) * 8]);
    COMPUTE_MB(0)
    if (pf) stageA(nbuf, 1, k0n);
    __builtin_amdgcn_s_barrier();
    __builtin_amdgcn_sched_barrier(0);
    COMPUTE_MB(1)
    if (pf) stageB(nbuf, k0n);
    __builtin_amdgcn_s_barrier();
    __builtin_amdgcn_sched_barrier(0);
    COMPUTE_MB(2)
    __builtin_amdgcn_s_barrier();
    __builtin_amdgcn_sched_barrier(0);
    COMPUTE_MB(3)
    __builtin_amdgcn_s_barrier();
  }

#pragma unroll
  for (int mb = 0; mb < 4; ++mb)
#pragma unroll
    for (int ni = 0; ni < 4; ++ni)
#pragma unroll
      for (int r = 0; r < 4; ++r)
        C[(size_t)(bm + wm * 64 + mb * 16 + lg * 4 + r) * N +
          bn + wn * 64 + ni * 16 + l16] = acc[mb][ni][r];
}

// ------------- rv: RoPE-K pack + V transpose in one launch -------------
__global__ __launch_bounds__(256) void rv_kernel(const u16* __restrict__ qkv,
                                                 const float* __restrict__ fc,
                                                 const float* __restrict__ fs,
                                                 u16* __restrict__ Kb,
                                                 u16* __restrict__ vt) {
  __shared__ u16 t[32][33];
  int bid = blockIdx.x;
  if (bid < 4096) {              // ---- rope K branch ----
    int kh = bid >> 10;
    int gi = (bid & 1023) * 256 + (int)threadIdx.x;   // (b*SEQ+s)*64 + i
    int i = gi & 63;
    int tt = gi >> 6;            // b*SEQ + s
    int s = tt & (SEQ - 1), b = tt >> 11;
    float c = fc[s * 64 + i], sn = fs[s * 64 + i];
    uint32_t pr = *reinterpret_cast<const uint32_t*>(&qkv[(size_t)tt * NQKV + NH * HD + kh * HD + 2 * i]);
    float tr = bf2f((u16)(pr & 0xffff)), ti = bf2f((u16)(pr >> 16));
    uint32_t w = (uint32_t)f2bf(tr * c - ti * sn) |
                 ((uint32_t)f2bf(tr * sn + ti * c) << 16);
    *reinterpret_cast<uint32_t*>(&Kb[((size_t)(b * NKV + kh) * SEQ + s) * HD + 2 * i]) = w;
    return;
  }
  int id = bid - 4096;           // 0..2047
  int bk = id >> 8;              // 0..7
  int rem = id & 255;
  int s0 = (rem >> 2) * 32;
  int d0 = (rem & 3) * 32;
  int b = bk >> 2, kh = bk & 3;
  int tx = threadIdx.x & 31, ty = threadIdx.x >> 5;   // ty 0..7
#pragma unroll
  for (int i = 0; i < 4; ++i) {
    int row = ty + i * 8;
    t[row][tx] = qkv[(size_t)(b * SEQ + s0 + row) * NQKV + NH * HD + NKV * HD + kh * HD + d0 + tx];
  }
  __syncthreads();
#pragma unroll
  for (int i = 0; i < 4; ++i) {
    int row = ty + i * 8;
    vt[((size_t)(b * NKV + kh) * HD + d0 + row) * SEQ + s0 + tx] = t[tx][row];
  }
}

// ---------------- causal flash attention (3 blocks/CU, V single-buffer) -------
// grid (1024): bid -> qblk = 31 - bid/32 (heavy first), bh = bid&31. One
// q-tile per block, 4 waves x 16 q-rows. LDS 52KB: K dbuf 32K, V single 16K,
// Ps [16][32] 4K (PV split into two key-halves reusing Ps). Counted waits:
// top vmcnt(0)+barrier (K[kt] resident, V write-hazard cleared); issue V(4)
// then K[kt+1](4); mid vmcnt(4)+barrier (V resident, K prefetch stays in
// flight). Swapped QK^T + in-register Q-RoPE + defer-max as round 10.
__global__ __launch_bounds__(256) void attn_kernel(const u16* __restrict__ qkv,
                                                   const float* __restrict__ fc,
                                                   const float* __restrict__ fs,
                                                   const u16* __restrict__ Kc,
                                                   const u16* __restrict__ VT,
                                                   u16* __restrict__ AO) {
  __shared__ u16 Ks[2][64 * 128];   // 32K, [key][d], swizzled, double-buffered
  __shared__ u16 Vs[128 * 64];      // 16K, [d][key], swizzled, single-buffered
  __shared__ u16 Ps[4][16 * 32];    // 4K, per-wave [q][32 keys] (half-tile)
  const int bid = blockIdx.x;
  const int qblk = 31 - (bid >> 5);
  const int bh = bid & 31;
  const int b = bh >> 4, h = bh & 15;
  const int kvh = h >> 2;
  const int tid = threadIdx.x, wave = tid >> 6, lane = tid & 63;
  const int l16 = lane & 15, lg = lane >> 4;
  const int qrow0 = qblk * 64 + wave * 16;
  const int rq = qrow0 + l16;     // this lane's q row

  const u16* Kbase = Kc + (size_t)(b * NKV + kvh) * SEQ * HD;
  const u16* Vbase = VT + (size_t)(b * NKV + kvh) * HD * SEQ;

  bf16x8 onesf;
#pragma unroll
  for (int j = 0; j < 8; ++j) onesf[j] = __builtin_bit_cast(__bf16, (u16)0x3F80);

  int kOff[4], vOff[4], kDst[4], vDst[4];
#pragma unroll
  for (int i = 0; i < 4; ++i) {
    int chunk = i * 4 + wave;                 // 0..15
    int krow = chunk * 4 + (lane >> 4);       // 0..63
    kOff[i] = krow * HD + ((lane & 15) ^ (krow & 15)) * 8;
    kDst[i] = chunk * 512;
    int vrow = chunk * 8 + (lane >> 3);       // 0..127
    vOff[i] = vrow * SEQ + ((lane & 7) ^ (vrow & 7)) * 8;
    vDst[i] = chunk * 512;
  }

  // ---- Q load + in-register RoPE ----
  const float qs = 0.12751689760098266f; // log2(e)/sqrt(128)
  const u16* Qrow = qkv + (size_t)(b * SEQ + rq) * NQKV + h * HD;
  const float* fcb = fc + (size_t)rq * 64;
  const float* fsb = fs + (size_t)rq * 64;
  bf16x8 qf[4];
#pragma unroll
  for (int c = 0; c < 4; ++c) {
    bf16x8 raw = load_frag(Qrow + c * 32 + lg * 8);
    float4 cc = *reinterpret_cast<const float4*>(fcb + c * 16 + lg * 4);
    float4 sv = *reinterpret_cast<const float4*>(fsb + c * 16 + lg * 4);
    bf16x8 q;
#pragma unroll
    for (int j = 0; j < 4; ++j) {
      float e = (float)raw[2 * j], od = (float)raw[2 * j + 1];
      float ce = (&cc.x)[j] * qs, se = (&sv.x)[j] * qs;
      q[2 * j]     = (__bf16)(e * ce - od * se);
      q[2 * j + 1] = (__bf16)(e * se + od * ce);
    }
    qf[c] = q;
  }

  f32x4 o[8] = {};
  f32x4 lsum = {};
  float m = -3e38f;

  // prologue: stage K[0]
#pragma unroll
  for (int i = 0; i < 4; ++i) async16(&Ks[0][kDst[i]], Kbase + kOff[i]);

  for (int kt = 0; kt <= qblk; ++kt) {
    const int cur = kt & 1;
    // top: own K[kt] (and Q) drained; barrier clears V/K-buf hazards
    asm volatile("s_waitcnt vmcnt(0)" ::: "memory");
    __builtin_amdgcn_s_barrier();
    __builtin_amdgcn_sched_barrier(0);
    // issue V[kt] (older 4), then K[kt+1] (newer 4)
    {
      const int k0 = kt * 64;
#pragma unroll
      for (int i = 0; i < 4; ++i) async16(&Vs[vDst[i]], Vbase + k0 + vOff[i]);
      if (kt < qblk) {
        const int k0n = (kt + 1) * 64;
#pragma unroll
        for (int i = 0; i < 4; ++i)
          async16(&Ks[cur ^ 1][kDst[i]], Kbase + (size_t)k0n * HD + kOff[i]);
      }
    }

    // QK^T swapped: s[cb][r] = S[key = kt*64+cb*16+lg*4+r][q = l16]
    f32x4 s[4] = {};
    __builtin_amdgcn_s_setprio(1);
#pragma unroll
    for (int cb = 0; cb < 4; ++cb) {
#pragma unroll
      for (int c = 0; c < 4; ++c) {
        bf16x8 kf = load_frag(&Ks[cur][(cb * 16 + l16) * 128 + (((c * 4 + lg) ^ l16) & 15) * 8]);
        s[cb] = __builtin_amdgcn_mfma_f32_16x16x32_bf16(kf, qf[c], s[cb], 0, 0, 0);
      }
    }
    __builtin_amdgcn_s_setprio(0);

    if (kt == qblk) { // diagonal tile: causal mask
      const int k0 = kt * 64;
#pragma unroll
      for (int cb = 0; cb < 4; ++cb) {
#pragma unroll
        for (int r = 0; r < 4; ++r) {
          int key = k0 + cb * 16 + lg * 4 + r;
          if (key > rq) s[cb][r] = -1e30f;
        }
      }
    }

    // per-lane tile max (q = l16)
    float v0 = fmaxf(fmaxf(fmaxf(s[0][0], s[0][1]), fmaxf(s[0][2], s[0][3])),
                     fmaxf(fmaxf(s[1][0], s[1][1]), fmaxf(s[1][2], s[1][3])));
    v0 = fmaxf(v0, fmaxf(fmaxf(fmaxf(s[2][0], s[2][1]), fmaxf(s[2][2], s[2][3])),
                         fmaxf(fmaxf(s[3][0], s[3][1]), fmaxf(s[3][2], s[3][3]))));
    v0 = fmaxf(v0, __shfl_xor(v0, 16));
    v0 = fmaxf(v0, __shfl_xor(v0, 32));

    bool need = v0 > m + 8.f;
    if (__any(need)) {
      float newm = fmaxf(m, v0);
      float sc = exp2f(m - newm);
      m = newm;
      float scR[4];
#pragma unroll
      for (int r = 0; r < 4; ++r) scR[r] = __shfl(sc, lg * 4 + r);
#pragma unroll
      for (int r = 0; r < 4; ++r) {
        lsum[r] *= scR[r];
#pragma unroll
        for (int db = 0; db < 8; ++db) o[db][r] *= scR[r];
      }
    }

    // exp2 + write Ps half0 (keys 0..31: cb=0,1)
#pragma unroll
    for (int cb = 0; cb < 2; ++cb) {
      uint32_t lo = (uint32_t)f2bf(exp2f(s[cb][0] - m)) |
                    ((uint32_t)f2bf(exp2f(s[cb][1] - m)) << 16);
      uint32_t hi = (uint32_t)f2bf(exp2f(s[cb][2] - m)) |
                    ((uint32_t)f2bf(exp2f(s[cb][3] - m)) << 16);
      uint64_t w = (uint64_t)lo | ((uint64_t)hi << 32);
      *reinterpret_cast<uint64_t*>(&Ps[wave][l16 * 32 + cb * 16 + lg * 4]) = w;
    }

    // mid: own V[kt] resident (K prefetch's 4 newer loads stay in flight)
    if (kt < qblk) { asm volatile("s_waitcnt vmcnt(4)" ::: "memory"); }
    else           { asm volatile("s_waitcnt vmcnt(0)" ::: "memory"); }
    __builtin_amdgcn_s_barrier();
    __builtin_amdgcn_sched_barrier(0);

    // PV half0 (keys 0..31, V slots c=0)
    {
      bf16x8 pf = load_frag(&Ps[wave][l16 * 32 + lg * 8]);
      __builtin_amdgcn_s_setprio(1);
      lsum = __builtin_amdgcn_mfma_f32_16x16x32_bf16(pf, onesf, lsum, 0, 0, 0);
#pragma unroll
      for (int db = 0; db < 8; ++db) {
        bf16x8 vf = load_frag(&Vs[(db * 16 + l16) * 64 + ((lg) ^ (l16 & 7)) * 8]);
        o[db] = __builtin_amdgcn_mfma_f32_16x16x32_bf16(pf, vf, o[db], 0, 0, 0);
      }
      __builtin_amdgcn_s_setprio(0);
    }

    // exp2 + write Ps half1 (keys 32..63: cb=2,3) — same-wave DS is in-order
#pragma unroll
    for (int cb = 2; cb < 4; ++cb) {
      uint32_t lo = (uint32_t)f2bf(exp2f(s[cb][0] - m)) |
                    ((uint32_t)f2bf(exp2f(s[cb][1] - m)) << 16);
      uint32_t hi = (uint32_t)f2bf(exp2f(s[cb][2] - m)) |
                    ((uint32_t)f2bf(exp2f(s[cb][3] - m)) << 16);
      uint64_t w = (uint64_t)lo | ((uint64_t)hi << 32);
      *reinterpret_cast<uint64_t*>(&Ps[wave][l16 * 32 + (cb - 2) * 16 + lg * 4]) = w;
    }

    // PV half1 (keys 32..63, V slots c=1)
    {
      bf16x8 pf = load_frag(&Ps[wave][l16 * 32 + lg * 8]);
      __builtin_amdgcn_s_setprio(1);
      lsum = __builtin_amdgcn_mfma_f32_16x16x32_bf16(pf, onesf, lsum, 0, 0, 0);
#pragma unroll
      for (int db = 0; db < 8; ++db) {
        bf16x8 vf = load_frag(&Vs[(db * 16 + l16) * 64 + ((4 + lg) ^ (l16 & 7)) * 8]);
        o[db] = __builtin_amdgcn_mfma_f32_16x16x32_bf16(pf, vf, o[db], 0, 0, 0);
      }
      __builtin_amdgcn_s_setprio(0);
    }
  }

#pragma unroll
  for (int r = 0; r < 4; ++r) {
    float inv = 1.f / lsum[r];
    int rqo = qrow0 + lg * 4 + r;
    size_t dst = ((size_t)(b * SEQ + rqo) * NH + h) * HD;
#pragma unroll
    for (int db = 0; db < 8; ++db)
      AO[dst + db * 16 + l16] = f2bf(o[db][r] * inv);
  }
}

extern "C" void kernel_launch(void* const* d_in, const int* in_sizes, int n_in,
                              void* d_out, int out_size, void* d_ws, size_t ws_size,
                              hipStream_t stream) {
  (void)in_sizes; (void)n_in; (void)out_size; (void)ws_size;
  const float* x  = (const float*)d_in[0];
  const float* fc = (const float*)d_in[1];
  const float* fs = (const float*)d_in[2];
  const float* wq = (const float*)d_in[3];
  const float* wk = (const float*)d_in[4];
  const float* wv = (const float*)d_in[5];
  const float* wo = (const float*)d_in[6];
  float* out = (float*)d_out;

  char* ws = (char*)d_ws;
  u16*  xb    = (u16*)(ws);                      // 16,777,216
  u16*  wtqkv = (u16*)(ws + 16777216);           // 12,582,912
  u16*  wto   = (u16*)(ws + 29360128);           //  8,388,608
  u16*  qkv   = (u16*)(ws + 37748736);           // 25,165,824 (bf16)
  u16*  Kb    = (u16*)(ws + 62914560);           //  4,194,304
  u16*  VTb   = (u16*)(ws + 67108864);           //  4,194,304
  u16*  AOb   = (u16*)(ws + 71303168);           // 16,777,216

  prep_kernel<<<dim3(32, 336), dim3(256), 0, stream>>>(x, wq, wk, wv, wo, xb, wtqkv, wto);

  gemm8p_kernel<true><<<dim3(192), dim3(512), 0, stream>>>(xb, wtqkv, qkv, MROWS, NQKV, DIMSZ, 12);

  rv_kernel<<<dim3(6144), dim3(256), 0, stream>>>(qkv, fc, fs, Kb, VTb);

  attn_kernel<<<dim3(1024), dim3(256), 0, stream>>>(qkv, fc, fs, Kb, VTb, AOb);

  gemm8p_n128_kernel<<<dim3(256), dim3(512), 0, stream>>>(AOb, wto, out, MROWS, DIMSZ, DIMSZ, 16);
}

// Round 17
// 192.854 us; speedup vs baseline: 1.0114x; 1.0114x over previous
//
#include <hip/hip_runtime.h>
#include <stdint.h>

#define DIMSZ 2048
#define NH 16
#define NKV 4
#define HD 128
#define BATCH 2
#define SEQ 2048
#define MROWS (BATCH*SEQ)          // 4096
#define NQKV (NH*HD + 2*NKV*HD)    // 3072

typedef unsigned short u16;
typedef float f32x4 __attribute__((ext_vector_type(4)));
typedef short short8 __attribute__((ext_vector_type(8)));
typedef __bf16 bf16x8 __attribute__((ext_vector_type(8)));
typedef unsigned short u16x4 __attribute__((ext_vector_type(4)));
typedef unsigned short u16x8 __attribute__((ext_vector_type(8)));

__device__ __forceinline__ u16 f2bf(float f) {
  __bf16 h = (__bf16)f;           // native RNE convert
  return __builtin_bit_cast(u16, h);
}

__device__ __forceinline__ float bf2f(u16 h) {
  union { uint32_t u; float f; } v; v.u = ((uint32_t)h) << 16; return v.f;
}

__device__ __forceinline__ void async16(void* lds, const void* g) {
  __builtin_amdgcn_global_load_lds(
      (const __attribute__((address_space(1))) void*)(g),
      (__attribute__((address_space(3))) void*)(lds), 16, 0, 0);
}

__device__ __forceinline__ bf16x8 load_frag(const u16* p) {
  short8 v = *reinterpret_cast<const short8*>(p);
  return __builtin_bit_cast(bf16x8, v);
}

// ------------- prep: x cast + merged transpose-cast of all 4 weights -------------
__global__ __launch_bounds__(256) void prep_kernel(const float* __restrict__ x,
                                                   const float* __restrict__ wq,
                                                   const float* __restrict__ wk,
                                                   const float* __restrict__ wv,
                                                   const float* __restrict__ wo,
                                                   u16* __restrict__ xb,
                                                   u16* __restrict__ wtqkv,
                                                   u16* __restrict__ wto) {
  __shared__ float tb[64][65];
  int y = blockIdx.y;
  if (y >= 80) {                 // ---- x cast branch ----
    int id = (y - 80) * 32 + blockIdx.x;            // 0..8191
    int i = (id * 256 + (int)threadIdx.x) * 4;
    float4 v = *reinterpret_cast<const float4*>(x + i);
    u16x4 o;
    o.x = f2bf(v.x); o.y = f2bf(v.y); o.z = f2bf(v.z); o.w = f2bf(v.w);
    *reinterpret_cast<u16x4*>(xb + i) = o;
    return;
  }
  const float* src; int srcN; u16* dst; int nbase;
  if (y < 32)      { src = wq; srcN = 2048; dst = wtqkv;                        nbase = y * 64; }
  else if (y < 40) { src = wk; srcN = 512;  dst = wtqkv + (size_t)2048 * 2048;  nbase = (y - 32) * 64; }
  else if (y < 48) { src = wv; srcN = 512;  dst = wtqkv + (size_t)2560 * 2048;  nbase = (y - 40) * 64; }
  else             { src = wo; srcN = 2048; dst = wto;                          nbase = (y - 48) * 64; }
  int k0 = blockIdx.x * 64;
  int t = threadIdx.x;
  int lr = t >> 4, lc = (t & 15) * 4;
#pragma unroll
  for (int i = 0; i < 4; ++i) {
    int row = lr + i * 16;
    float4 v = *reinterpret_cast<const float4*>(&src[(size_t)(k0 + row) * srcN + nbase + lc]);
    tb[row][lc] = v.x; tb[row][lc + 1] = v.y; tb[row][lc + 2] = v.z; tb[row][lc + 3] = v.w;
  }
  __syncthreads();
  int n = t >> 3, kg = (t & 7) * 8;
#pragma unroll
  for (int i = 0; i < 2; ++i) {
    int nn = n + i * 32;
    u16x8 o;
#pragma unroll
    for (int j = 0; j < 8; ++j) o[j] = f2bf(tb[kg + j][nn]);
    *reinterpret_cast<u16x8*>(&dst[(size_t)(nbase + nn) * 2048 + k0 + kg]) = o;
  }
}

// ---------------- 8-phase-style 256x256 GEMM (gemm1) ----------------
#define COMPUTE_PAIR(q)                                                              \
  {                                                                                  \
    bf16x8 af[2][2];                                                                 \
    _Pragma("unroll")                                                                \
    for (int m2 = 0; m2 < 2; ++m2)                                                   \
      _Pragma("unroll")                                                              \
      for (int kk = 0; kk < 2; ++kk)                                                 \
        af[m2][kk] = load_frag(&lds[buf][0][wm * 8192 +                              \
            (((q) * 2 + m2) * 16 + l16) * 64 + ((kk * 4 + lg) ^ (l16 & 7)) * 8]);    \
    __builtin_amdgcn_s_setprio(1);                                                   \
    _Pragma("unroll")                                                                \
    for (int m2 = 0; m2 < 2; ++m2)                                                   \
      _Pragma("unroll")                                                              \
      for (int ni = 0; ni < 4; ++ni)                                                 \
        _Pragma("unroll")                                                            \
        for (int kk = 0; kk < 2; ++kk)                                               \
          acc[(q) * 2 + m2][ni] = __builtin_amdgcn_mfma_f32_16x16x32_bf16(           \
              af[m2][kk], bper[ni][kk], acc[(q) * 2 + m2][ni], 0, 0, 0);             \
    __builtin_amdgcn_s_setprio(0);                                                   \
  }

template <bool BF16OUT>
__global__ __launch_bounds__(512, 2) void gemm8p_kernel(const u16* __restrict__ A,
                                                        const u16* __restrict__ BT,
                                                        void* __restrict__ Cp,
                                                        int M, int N, int K, int gx) {
  __shared__ u16 lds[2][2][16384];   // [buf][A/B][256 rows x 64] = 128 KiB
  const int tid = threadIdx.x;
  const int wave = tid >> 6, lane = tid & 63;
  const int l16 = lane & 15, lg = lane >> 4;
  const int wm = wave >> 2, wn = wave & 3;
  const int rloc = lane >> 3;
  const int sOff = ((lane & 7) ^ rloc) * 8;
  const int nwg = gridDim.x;
  const int swz = (blockIdx.x & 7) * (nwg >> 3) + (blockIdx.x >> 3);
  const int bm = (swz / gx) * 256, bn = (swz % gx) * 256;

  f32x4 acc[8][4] = {};

  auto stage = [&](int dstbuf, int x, int h, const u16* xp, int xr0, int kk0) {
#pragma unroll
    for (int j = 0; j < 2; ++j) {
      int c = j * 8 + wave;   // 0..15, 1KB chunk = 8 rows
      async16(&lds[dstbuf][x][h * 8192 + c * 512],
              xp + (size_t)(xr0 + h * 128 + c * 8 + rloc) * K + kk0 + sOff);
    }
  };

  stage(0, 0, 0, A, bm, 0);
  stage(0, 0, 1, A, bm, 0);
  stage(0, 1, 0, BT, bn, 0);
  stage(0, 1, 1, BT, bn, 0);

  const int NT = K >> 6;
  for (int kt = 0; kt < NT; ++kt) {
    const int buf = kt & 1, nbuf = buf ^ 1;
    const int k0n = (kt + 1) << 6;
    const bool pf = (kt + 1 < NT);
    bf16x8 bper[4][2];

    if (pf) {
      stage(nbuf, 0, 0, A, bm, k0n);
      asm volatile("s_waitcnt vmcnt(2)" ::: "memory");
    } else {
      asm volatile("s_waitcnt vmcnt(0)" ::: "memory");
    }
    __builtin_amdgcn_s_barrier();
    __builtin_amdgcn_sched_barrier(0);
#pragma unroll
    for (int ni = 0; ni < 4; ++ni)
#pragma unroll
      for (int kk = 0; kk < 2; ++kk)
        bper[ni][kk] = load_frag(&lds[buf][1][(wn >> 1) * 8192 +
            ((wn & 1) * 64 + ni * 16 + l16) * 64 + ((kk * 4 + lg) ^ (l16 & 7)) * 8]);
    COMPUTE_PAIR(0)
    if (pf) stage(nbuf, 0, 1, A, bm, k0n);
    __builtin_amdgcn_s_barrier();
    __builtin_amdgcn_sched_barrier(0);
    COMPUTE_PAIR(1)
    if (pf) stage(nbuf, 1, 0, BT, bn, k0n);
    __builtin_amdgcn_s_barrier();
    __builtin_amdgcn_sched_barrier(0);
    COMPUTE_PAIR(2)
    if (pf) stage(nbuf, 1, 1, BT, bn, k0n);
    __builtin_amdgcn_s_barrier();
    __builtin_amdgcn_sched_barrier(0);
    COMPUTE_PAIR(3)
    __builtin_amdgcn_s_barrier();
  }

#pragma unroll
  for (int mi = 0; mi < 8; ++mi)
#pragma unroll
    for (int ni = 0; ni < 4; ++ni)
#pragma unroll
      for (int r = 0; r < 4; ++r) {
        size_t idx = (size_t)(bm + wm * 128 + mi * 16 + lg * 4 + r) * N +
                     bn + wn * 64 + ni * 16 + l16;
        if (BF16OUT) ((u16*)Cp)[idx] = f2bf(acc[mi][ni][r]);
        else         ((float*)Cp)[idx] = acc[mi][ni][r];
      }
}

// ---------------- 8-phase-style 256x128 GEMM (gemm2, fp32 out) ----------------
#define COMPUTE_MB(q)                                                                \
  {                                                                                  \
    bf16x8 af[2];                                                                    \
    _Pragma("unroll")                                                                \
    for (int kk = 0; kk < 2; ++kk)                                                   \
      af[kk] = load_frag(&lds2[buf][(wm * 64 + (q) * 16 + l16) * 64 +                \
                                    ((kk * 4 + lg) ^ (l16 & 7)) * 8]);               \
    __builtin_amdgcn_s_setprio(1);                                                   \
    _Pragma("unroll")                                                                \
    for (int ni = 0; ni < 4; ++ni)                                                   \
      _Pragma("unroll")                                                              \
      for (int kk = 0; kk < 2; ++kk)                                                 \
        acc[(q)][ni] = __builtin_amdgcn_mfma_f32_16x16x32_bf16(                      \
            af[kk], bper[ni][kk], acc[(q)][ni], 0, 0, 0);                            \
    __builtin_amdgcn_s_setprio(0);                                                   \
  }

__global__ __launch_bounds__(512, 2) void gemm8p_n128_kernel(const u16* __restrict__ A,
                                                             const u16* __restrict__ BT,
                                                             float* __restrict__ C,
                                                             int M, int N, int K, int gx) {
  __shared__ u16 lds2[2][24576];   // [buf][A 256x64 | B 128x64] = 96 KiB
  const int tid = threadIdx.x;
  const int wave = tid >> 6, lane = tid & 63;
  const int l16 = lane & 15, lg = lane >> 4;
  const int wm = wave >> 1, wn = wave & 1;
  const int rloc = lane >> 3;
  const int sOff = ((lane & 7) ^ rloc) * 8;
  const int nwg = gridDim.x;
  const int swz = (blockIdx.x & 7) * (nwg >> 3) + (blockIdx.x >> 3);
  const int bm = (swz / gx) * 256, bn = (swz % gx) * 128;

  f32x4 acc[4][4] = {};

  auto stageA = [&](int dstbuf, int h, int kk0) {
#pragma unroll
    for (int j = 0; j < 2; ++j) {
      int c = j * 8 + wave;
      async16(&lds2[dstbuf][h * 8192 + c * 512],
              A + (size_t)(bm + h * 128 + c * 8 + rloc) * K + kk0 + sOff);
    }
  };
  auto stageB = [&](int dstbuf, int kk0) {
#pragma unroll
    for (int j = 0; j < 2; ++j) {
      int c = j * 8 + wave;
      async16(&lds2[dstbuf][16384 + c * 512],
              BT + (size_t)(bn + c * 8 + rloc) * K + kk0 + sOff);
    }
  };

  stageA(0, 0, 0);
  stageA(0, 1, 0);
  stageB(0, 0);

  const int NT = K >> 6;
  for (int kt = 0; kt < NT; ++kt) {
    const int buf = kt & 1, nbuf = buf ^ 1;
    const int k0n = (kt + 1) << 6;
    const bool pf = (kt + 1 < NT);
    bf16x8 bper[4][2];

    if (pf) {
      stageA(nbuf, 0, k0n);
      asm volatile("s_waitcnt vmcnt(2)" ::: "memory");
    } else {
      asm volatile("s_waitcnt vmcnt(0)" ::: "memory");
    }
    __builtin_amdgcn_s_barrier();
    __builtin_amdgcn_sched_barrier(0);
#pragma unroll
    for (int ni = 0; ni < 4; ++ni)
#pragma unroll
      for (int kk = 0; kk < 2; ++kk)
        bper[ni][kk] = load_frag(&lds2[buf][16384 +
            (wn * 64 + ni * 16 + l16) * 64 + ((kk * 4 + lg) ^ (l16 & 7)) * 8]);
    COMPUTE_MB(0)
    if (pf) stageA(nbuf, 1, k0n);
    __builtin_amdgcn_s_barrier();
    __builtin_amdgcn_sched_barrier(0);
    COMPUTE_MB(1)
    if (pf) stageB(nbuf, k0n);
    __builtin_amdgcn_s_barrier();
    __builtin_amdgcn_sched_barrier(0);
    COMPUTE_MB(2)
    __builtin_amdgcn_s_barrier();
    __builtin_amdgcn_sched_barrier(0);
    COMPUTE_MB(3)
    __builtin_amdgcn_s_barrier();
  }

#pragma unroll
  for (int mb = 0; mb < 4; ++mb)
#pragma unroll
    for (int ni = 0; ni < 4; ++ni)
#pragma unroll
      for (int r = 0; r < 4; ++r)
        C[(size_t)(bm + wm * 64 + mb * 16 + lg * 4 + r) * N +
          bn + wn * 64 + ni * 16 + l16] = acc[mb][ni][r];
}

// ------------- rv: RoPE-K pack + V transpose in one launch -------------
__global__ __launch_bounds__(256) void rv_kernel(const u16* __restrict__ qkv,
                                                 const float* __restrict__ fc,
                                                 const float* __restrict__ fs,
                                                 u16* __restrict__ Kb,
                                                 u16* __restrict__ vt) {
  __shared__ u16 t[32][33];
  int bid = blockIdx.x;
  if (bid < 4096) {              // ---- rope K branch ----
    int kh = bid >> 10;
    int gi = (bid & 1023) * 256 + (int)threadIdx.x;   // (b*SEQ+s)*64 + i
    int i = gi & 63;
    int tt = gi >> 6;            // b*SEQ + s
    int s = tt & (SEQ - 1), b = tt >> 11;
    float c = fc[s * 64 + i], sn = fs[s * 64 + i];
    uint32_t pr = *reinterpret_cast<const uint32_t*>(&qkv[(size_t)tt * NQKV + NH * HD + kh * HD + 2 * i]);
    float tr = bf2f((u16)(pr & 0xffff)), ti = bf2f((u16)(pr >> 16));
    uint32_t w = (uint32_t)f2bf(tr * c - ti * sn) |
                 ((uint32_t)f2bf(tr * sn + ti * c) << 16);
    *reinterpret_cast<uint32_t*>(&Kb[((size_t)(b * NKV + kh) * SEQ + s) * HD + 2 * i]) = w;
    return;
  }
  int id = bid - 4096;           // 0..2047
  int bk = id >> 8;              // 0..7
  int rem = id & 255;
  int s0 = (rem >> 2) * 32;
  int d0 = (rem & 3) * 32;
  int b = bk >> 2, kh = bk & 3;
  int tx = threadIdx.x & 31, ty = threadIdx.x >> 5;   // ty 0..7
#pragma unroll
  for (int i = 0; i < 4; ++i) {
    int row = ty + i * 8;
    t[row][tx] = qkv[(size_t)(b * SEQ + s0 + row) * NQKV + NH * HD + NKV * HD + kh * HD + d0 + tx];
  }
  __syncthreads();
#pragma unroll
  for (int i = 0; i < 4; ++i) {
    int row = ty + i * 8;
    vt[((size_t)(b * NKV + kh) * HD + d0 + row) * SEQ + s0 + tx] = t[tx][row];
  }
}

// ---------------- causal flash attention (3 blocks/CU, V single-buffer) -------
// Round-16 structure with the Ps bank-conflict FIXED: Ps rows padded 32->40 u16
// (80 B = 5x16B keeps b128 reads aligned; row-to-bank stride 20 spreads 16 rows
// over 8 bank-quads, 2 lanes each = conflict-free). LDS 54272 B -> 3 blocks/CU.
__global__ __launch_bounds__(256) void attn_kernel(const u16* __restrict__ qkv,
                                                   const float* __restrict__ fc,
                                                   const float* __restrict__ fs,
                                                   const u16* __restrict__ Kc,
                                                   const u16* __restrict__ VT,
                                                   u16* __restrict__ AO) {
  __shared__ u16 Ks[2][64 * 128];   // 32K, [key][d], swizzled, double-buffered
  __shared__ u16 Vs[128 * 64];      // 16K, [d][key], swizzled, single-buffered
  __shared__ u16 Ps[4][16 * 40];    // 5K, per-wave [q][32 keys], rows padded to 40
  const int bid = blockIdx.x;
  const int qblk = 31 - (bid >> 5);
  const int bh = bid & 31;
  const int b = bh >> 4, h = bh & 15;
  const int kvh = h >> 2;
  const int tid = threadIdx.x, wave = tid >> 6, lane = tid & 63;
  const int l16 = lane & 15, lg = lane >> 4;
  const int qrow0 = qblk * 64 + wave * 16;
  const int rq = qrow0 + l16;     // this lane's q row

  const u16* Kbase = Kc + (size_t)(b * NKV + kvh) * SEQ * HD;
  const u16* Vbase = VT + (size_t)(b * NKV + kvh) * HD * SEQ;

  bf16x8 onesf;
#pragma unroll
  for (int j = 0; j < 8; ++j) onesf[j] = __builtin_bit_cast(__bf16, (u16)0x3F80);

  int kOff[4], vOff[4], kDst[4], vDst[4];
#pragma unroll
  for (int i = 0; i < 4; ++i) {
    int chunk = i * 4 + wave;                 // 0..15
    int krow = chunk * 4 + (lane >> 4);       // 0..63
    kOff[i] = krow * HD + ((lane & 15) ^ (krow & 15)) * 8;
    kDst[i] = chunk * 512;
    int vrow = chunk * 8 + (lane >> 3);       // 0..127
    vOff[i] = vrow * SEQ + ((lane & 7) ^ (vrow & 7)) * 8;
    vDst[i] = chunk * 512;
  }

  // ---- Q load + in-register RoPE ----
  const float qs = 0.12751689760098266f; // log2(e)/sqrt(128)
  const u16* Qrow = qkv + (size_t)(b * SEQ + rq) * NQKV + h * HD;
  const float* fcb = fc + (size_t)rq * 64;
  const float* fsb = fs + (size_t)rq * 64;
  bf16x8 qf[4];
#pragma unroll
  for (int c = 0; c < 4; ++c) {
    bf16x8 raw = load_frag(Qrow + c * 32 + lg * 8);
    float4 cc = *reinterpret_cast<const float4*>(fcb + c * 16 + lg * 4);
    float4 sv = *reinterpret_cast<const float4*>(fsb + c * 16 + lg * 4);
    bf16x8 q;
#pragma unroll
    for (int j = 0; j < 4; ++j) {
      float e = (float)raw[2 * j], od = (float)raw[2 * j + 1];
      float ce = (&cc.x)[j] * qs, se = (&sv.x)[j] * qs;
      q[2 * j]     = (__bf16)(e * ce - od * se);
      q[2 * j + 1] = (__bf16)(e * se + od * ce);
    }
    qf[c] = q;
  }

  f32x4 o[8] = {};
  f32x4 lsum = {};
  float m = -3e38f;

  // prologue: stage K[0]
#pragma unroll
  for (int i = 0; i < 4; ++i) async16(&Ks[0][kDst[i]], Kbase + kOff[i]);

  for (int kt = 0; kt <= qblk; ++kt) {
    const int cur = kt & 1;
    // top: own K[kt] (and Q) drained; barrier clears V/K-buf hazards
    asm volatile("s_waitcnt vmcnt(0)" ::: "memory");
    __builtin_amdgcn_s_barrier();
    __builtin_amdgcn_sched_barrier(0);
    // issue V[kt] (older 4), then K[kt+1] (newer 4)
    {
      const int k0 = kt * 64;
#pragma unroll
      for (int i = 0; i < 4; ++i) async16(&Vs[vDst[i]], Vbase + k0 + vOff[i]);
      if (kt < qblk) {
        const int k0n = (kt + 1) * 64;
#pragma unroll
        for (int i = 0; i < 4; ++i)
          async16(&Ks[cur ^ 1][kDst[i]], Kbase + (size_t)k0n * HD + kOff[i]);
      }
    }

    // QK^T swapped: s[cb][r] = S[key = kt*64+cb*16+lg*4+r][q = l16]
    f32x4 s[4] = {};
    __builtin_amdgcn_s_setprio(1);
#pragma unroll
    for (int cb = 0; cb < 4; ++cb) {
#pragma unroll
      for (int c = 0; c < 4; ++c) {
        bf16x8 kf = load_frag(&Ks[cur][(cb * 16 + l16) * 128 + (((c * 4 + lg) ^ l16) & 15) * 8]);
        s[cb] = __builtin_amdgcn_mfma_f32_16x16x32_bf16(kf, qf[c], s[cb], 0, 0, 0);
      }
    }
    __builtin_amdgcn_s_setprio(0);

    if (kt == qblk) { // diagonal tile: causal mask
      const int k0 = kt * 64;
#pragma unroll
      for (int cb = 0; cb < 4; ++cb) {
#pragma unroll
        for (int r = 0; r < 4; ++r) {
          int key = k0 + cb * 16 + lg * 4 + r;
          if (key > rq) s[cb][r] = -1e30f;
        }
      }
    }

    // per-lane tile max (q = l16)
    float v0 = fmaxf(fmaxf(fmaxf(s[0][0], s[0][1]), fmaxf(s[0][2], s[0][3])),
                     fmaxf(fmaxf(s[1][0], s[1][1]), fmaxf(s[1][2], s[1][3])));
    v0 = fmaxf(v0, fmaxf(fmaxf(fmaxf(s[2][0], s[2][1]), fmaxf(s[2][2], s[2][3])),
                         fmaxf(fmaxf(s[3][0], s[3][1]), fmaxf(s[3][2], s[3][3]))));
    v0 = fmaxf(v0, __shfl_xor(v0, 16));
    v0 = fmaxf(v0, __shfl_xor(v0, 32));

    bool need = v0 > m + 8.f;
    if (__any(need)) {
      float newm = fmaxf(m, v0);
      float sc = exp2f(m - newm);
      m = newm;
      float scR[4];
#pragma unroll
      for (int r = 0; r < 4; ++r) scR[r] = __shfl(sc, lg * 4 + r);
#pragma unroll
      for (int r = 0; r < 4; ++r) {
        lsum[r] *= scR[r];
#pragma unroll
        for (int db = 0; db < 8; ++db) o[db][r] *= scR[r];
      }
    }

    // exp2 + write Ps half0 (keys 0..31: cb=0,1); rows padded to 40 u16
#pragma unroll
    for (int cb = 0; cb < 2; ++cb) {
      uint32_t lo = (uint32_t)f2bf(exp2f(s[cb][0] - m)) |
                    ((uint32_t)f2bf(exp2f(s[cb][1] - m)) << 16);
      uint32_t hi = (uint32_t)f2bf(exp2f(s[cb][2] - m)) |
                    ((uint32_t)f2bf(exp2f(s[cb][3] - m)) << 16);
      uint64_t w = (uint64_t)lo | ((uint64_t)hi << 32);
      *reinterpret_cast<uint64_t*>(&Ps[wave][l16 * 40 + cb * 16 + lg * 4]) = w;
    }

    // mid: own V[kt] resident (K prefetch's 4 newer loads stay in flight)
    if (kt < qblk) { asm volatile("s_waitcnt vmcnt(4)" ::: "memory"); }
    else           { asm volatile("s_waitcnt vmcnt(0)" ::: "memory"); }
    __builtin_amdgcn_s_barrier();
    __builtin_amdgcn_sched_barrier(0);

    // PV half0 (keys 0..31, V slots c=0)
    {
      bf16x8 pf = load_frag(&Ps[wave][l16 * 40 + lg * 8]);
      __builtin_amdgcn_s_setprio(1);
      lsum = __builtin_amdgcn_mfma_f32_16x16x32_bf16(pf, onesf, lsum, 0, 0, 0);
#pragma unroll
      for (int db = 0; db < 8; ++db) {
        bf16x8 vf = load_frag(&Vs[(db * 16 + l16) * 64 + ((lg) ^ (l16 & 7)) * 8]);
        o[db] = __builtin_amdgcn_mfma_f32_16x16x32_bf16(pf, vf, o[db], 0, 0, 0);
      }
      __builtin_amdgcn_s_setprio(0);
    }

    // exp2 + write Ps half1 (keys 32..63: cb=2,3) — same-wave DS is in-order
#pragma unroll
    for (int cb = 2; cb < 4; ++cb) {
      uint32_t lo = (uint32_t)f2bf(exp2f(s[cb][0] - m)) |
                    ((uint32_t)f2bf(exp2f(s[cb][1] - m)) << 16);
      uint32_t hi = (uint32_t)f2bf(exp2f(s[cb][2] - m)) |
                    ((uint32_t)f2bf(exp2f(s[cb][3] - m)) << 16);
      uint64_t w = (uint64_t)lo | ((uint64_t)hi << 32);
      *reinterpret_cast<uint64_t*>(&Ps[wave][l16 * 40 + (cb - 2) * 16 + lg * 4]) = w;
    }

    // PV half1 (keys 32..63, V slots c=1)
    {
      bf16x8 pf = load_frag(&Ps[wave][l16 * 40 + lg * 8]);
      __builtin_amdgcn_s_setprio(1);
      lsum = __builtin_amdgcn_mfma_f32_16x16x32_bf16(pf, onesf, lsum, 0, 0, 0);
#pragma unroll
      for (int db = 0; db < 8; ++db) {
        bf16x8 vf = load_frag(&Vs[(db * 16 + l16) * 64 + ((4 + lg) ^ (l16 & 7)) * 8]);
        o[db] = __builtin_amdgcn_mfma_f32_16x16x32_bf16(pf, vf, o[db], 0, 0, 0);
      }
      __builtin_amdgcn_s_setprio(0);
    }
  }

#pragma unroll
  for (int r = 0; r < 4; ++r) {
    float inv = 1.f / lsum[r];
    int rqo = qrow0 + lg * 4 + r;
    size_t dst = ((size_t)(b * SEQ + rqo) * NH + h) * HD;
#pragma unroll
    for (int db = 0; db < 8; ++db)
      AO[dst + db * 16 + l16] = f2bf(o[db][r] * inv);
  }
}

extern "C" void kernel_launch(void* const* d_in, const int* in_sizes, int n_in,
                              void* d_out, int out_size, void* d_ws, size_t ws_size,
                              hipStream_t stream) {
  (void)in_sizes; (void)n_in; (void)out_size; (void)ws_size;
  const float* x  = (const float*)d_in[0];
  const float* fc = (const float*)d_in[1];
  const float* fs = (const float*)d_in[2];
  const float* wq = (const float*)d_in[3];
  const float* wk = (const float*)d_in[4];
  const float* wv = (const float*)d_in[5];
  const float* wo = (const float*)d_in[6];
  float* out = (float*)d_out;

  char* ws = (char*)d_ws;
  u16*  xb    = (u16*)(ws);                      // 16,777,216
  u16*  wtqkv = (u16*)(ws + 16777216);           // 12,582,912
  u16*  wto   = (u16*)(ws + 29360128);           //  8,388,608
  u16*  qkv   = (u16*)(ws + 37748736);           // 25,165,824 (bf16)
  u16*  Kb    = (u16*)(ws + 62914560);           //  4,194,304
  u16*  VTb   = (u16*)(ws + 67108864);           //  4,194,304
  u16*  AOb   = (u16*)(ws + 71303168);           // 16,777,216

  prep_kernel<<<dim3(32, 336), dim3(256), 0, stream>>>(x, wq, wk, wv, wo, xb, wtqkv, wto);

  gemm8p_kernel<true><<<dim3(192), dim3(512), 0, stream>>>(xb, wtqkv, qkv, MROWS, NQKV, DIMSZ, 12);

  rv_kernel<<<dim3(6144), dim3(256), 0, stream>>>(qkv, fc, fs, Kb, VTb);

  attn_kernel<<<dim3(1024), dim3(256), 0, stream>>>(qkv, fc, fs, Kb, VTb, AOb);

  gemm8p_n128_kernel<<<dim3(256), dim3(512), 0, stream>>>(AOb, wto, out, MROWS, DIMSZ, DIMSZ, 16);
}

// Round 18
// 186.325 us; speedup vs baseline: 1.0469x; 1.0350x over previous
//
#include <hip/hip_runtime.h>
#include <stdint.h>

#define DIMSZ 2048
#define NH 16
#define NKV 4
#define HD 128
#define BATCH 2
#define SEQ 2048
#define MROWS (BATCH*SEQ)          // 4096
#define NQKV (NH*HD + 2*NKV*HD)    // 3072

typedef unsigned short u16;
typedef float f32x4 __attribute__((ext_vector_type(4)));
typedef short short8 __attribute__((ext_vector_type(8)));
typedef __bf16 bf16x8 __attribute__((ext_vector_type(8)));
typedef unsigned short u16x4 __attribute__((ext_vector_type(4)));
typedef unsigned short u16x8 __attribute__((ext_vector_type(8)));

__device__ __forceinline__ u16 f2bf(float f) {
  __bf16 h = (__bf16)f;           // native RNE convert
  return __builtin_bit_cast(u16, h);
}

__device__ __forceinline__ float bf2f(u16 h) {
  union { uint32_t u; float f; } v; v.u = ((uint32_t)h) << 16; return v.f;
}

__device__ __forceinline__ void async16(void* lds, const void* g) {
  __builtin_amdgcn_global_load_lds(
      (const __attribute__((address_space(1))) void*)(g),
      (__attribute__((address_space(3))) void*)(lds), 16, 0, 0);
}

__device__ __forceinline__ bf16x8 load_frag(const u16* p) {
  short8 v = *reinterpret_cast<const short8*>(p);
  return __builtin_bit_cast(bf16x8, v);
}

// ------------- prep: x cast + merged transpose-cast of all 4 weights -------------
__global__ __launch_bounds__(256) void prep_kernel(const float* __restrict__ x,
                                                   const float* __restrict__ wq,
                                                   const float* __restrict__ wk,
                                                   const float* __restrict__ wv,
                                                   const float* __restrict__ wo,
                                                   u16* __restrict__ xb,
                                                   u16* __restrict__ wtqkv,
                                                   u16* __restrict__ wto) {
  __shared__ float tb[64][65];
  int y = blockIdx.y;
  if (y >= 80) {                 // ---- x cast branch ----
    int id = (y - 80) * 32 + blockIdx.x;            // 0..8191
    int i = (id * 256 + (int)threadIdx.x) * 4;
    float4 v = *reinterpret_cast<const float4*>(x + i);
    u16x4 o;
    o.x = f2bf(v.x); o.y = f2bf(v.y); o.z = f2bf(v.z); o.w = f2bf(v.w);
    *reinterpret_cast<u16x4*>(xb + i) = o;
    return;
  }
  const float* src; int srcN; u16* dst; int nbase;
  if (y < 32)      { src = wq; srcN = 2048; dst = wtqkv;                        nbase = y * 64; }
  else if (y < 40) { src = wk; srcN = 512;  dst = wtqkv + (size_t)2048 * 2048;  nbase = (y - 32) * 64; }
  else if (y < 48) { src = wv; srcN = 512;  dst = wtqkv + (size_t)2560 * 2048;  nbase = (y - 40) * 64; }
  else             { src = wo; srcN = 2048; dst = wto;                          nbase = (y - 48) * 64; }
  int k0 = blockIdx.x * 64;
  int t = threadIdx.x;
  int lr = t >> 4, lc = (t & 15) * 4;
#pragma unroll
  for (int i = 0; i < 4; ++i) {
    int row = lr + i * 16;
    float4 v = *reinterpret_cast<const float4*>(&src[(size_t)(k0 + row) * srcN + nbase + lc]);
    tb[row][lc] = v.x; tb[row][lc + 1] = v.y; tb[row][lc + 2] = v.z; tb[row][lc + 3] = v.w;
  }
  __syncthreads();
  int n = t >> 3, kg = (t & 7) * 8;
#pragma unroll
  for (int i = 0; i < 2; ++i) {
    int nn = n + i * 32;
    u16x8 o;
#pragma unroll
    for (int j = 0; j < 8; ++j) o[j] = f2bf(tb[kg + j][nn]);
    *reinterpret_cast<u16x8*>(&dst[(size_t)(nbase + nn) * 2048 + k0 + kg]) = o;
  }
}

// ---------------- 8-phase-style 256x256 GEMM (gemm1) ----------------
#define COMPUTE_PAIR(q)                                                              \
  {                                                                                  \
    bf16x8 af[2][2];                                                                 \
    _Pragma("unroll")                                                                \
    for (int m2 = 0; m2 < 2; ++m2)                                                   \
      _Pragma("unroll")                                                              \
      for (int kk = 0; kk < 2; ++kk)                                                 \
        af[m2][kk] = load_frag(&lds[buf][0][wm * 8192 +                              \
            (((q) * 2 + m2) * 16 + l16) * 64 + ((kk * 4 + lg) ^ (l16 & 7)) * 8]);    \
    __builtin_amdgcn_s_setprio(1);                                                   \
    _Pragma("unroll")                                                                \
    for (int m2 = 0; m2 < 2; ++m2)                                                   \
      _Pragma("unroll")                                                              \
      for (int ni = 0; ni < 4; ++ni)                                                 \
        _Pragma("unroll")                                                            \
        for (int kk = 0; kk < 2; ++kk)                                               \
          acc[(q) * 2 + m2][ni] = __builtin_amdgcn_mfma_f32_16x16x32_bf16(           \
              af[m2][kk], bper[ni][kk], acc[(q) * 2 + m2][ni], 0, 0, 0);             \
    __builtin_amdgcn_s_setprio(0);                                                   \
  }

template <bool BF16OUT>
__global__ __launch_bounds__(512, 2) void gemm8p_kernel(const u16* __restrict__ A,
                                                        const u16* __restrict__ BT,
                                                        void* __restrict__ Cp,
                                                        int M, int N, int K, int gx) {
  __shared__ u16 lds[2][2][16384];   // [buf][A/B][256 rows x 64] = 128 KiB
  const int tid = threadIdx.x;
  const int wave = tid >> 6, lane = tid & 63;
  const int l16 = lane & 15, lg = lane >> 4;
  const int wm = wave >> 2, wn = wave & 3;
  const int rloc = lane >> 3;
  const int sOff = ((lane & 7) ^ rloc) * 8;
  const int nwg = gridDim.x;
  const int swz = (blockIdx.x & 7) * (nwg >> 3) + (blockIdx.x >> 3);
  const int bm = (swz / gx) * 256, bn = (swz % gx) * 256;

  f32x4 acc[8][4] = {};

  auto stage = [&](int dstbuf, int x, int h, const u16* xp, int xr0, int kk0) {
#pragma unroll
    for (int j = 0; j < 2; ++j) {
      int c = j * 8 + wave;   // 0..15, 1KB chunk = 8 rows
      async16(&lds[dstbuf][x][h * 8192 + c * 512],
              xp + (size_t)(xr0 + h * 128 + c * 8 + rloc) * K + kk0 + sOff);
    }
  };

  stage(0, 0, 0, A, bm, 0);
  stage(0, 0, 1, A, bm, 0);
  stage(0, 1, 0, BT, bn, 0);
  stage(0, 1, 1, BT, bn, 0);

  const int NT = K >> 6;
  for (int kt = 0; kt < NT; ++kt) {
    const int buf = kt & 1, nbuf = buf ^ 1;
    const int k0n = (kt + 1) << 6;
    const bool pf = (kt + 1 < NT);
    bf16x8 bper[4][2];

    if (pf) {
      stage(nbuf, 0, 0, A, bm, k0n);
      asm volatile("s_waitcnt vmcnt(2)" ::: "memory");
    } else {
      asm volatile("s_waitcnt vmcnt(0)" ::: "memory");
    }
    __builtin_amdgcn_s_barrier();
    __builtin_amdgcn_sched_barrier(0);
#pragma unroll
    for (int ni = 0; ni < 4; ++ni)
#pragma unroll
      for (int kk = 0; kk < 2; ++kk)
        bper[ni][kk] = load_frag(&lds[buf][1][(wn >> 1) * 8192 +
            ((wn & 1) * 64 + ni * 16 + l16) * 64 + ((kk * 4 + lg) ^ (l16 & 7)) * 8]);
    COMPUTE_PAIR(0)
    if (pf) stage(nbuf, 0, 1, A, bm, k0n);
    __builtin_amdgcn_s_barrier();
    __builtin_amdgcn_sched_barrier(0);
    COMPUTE_PAIR(1)
    if (pf) stage(nbuf, 1, 0, BT, bn, k0n);
    __builtin_amdgcn_s_barrier();
    __builtin_amdgcn_sched_barrier(0);
    COMPUTE_PAIR(2)
    if (pf) stage(nbuf, 1, 1, BT, bn, k0n);
    __builtin_amdgcn_s_barrier();
    __builtin_amdgcn_sched_barrier(0);
    COMPUTE_PAIR(3)
    __builtin_amdgcn_s_barrier();
  }

#pragma unroll
  for (int mi = 0; mi < 8; ++mi)
#pragma unroll
    for (int ni = 0; ni < 4; ++ni)
#pragma unroll
      for (int r = 0; r < 4; ++r) {
        size_t idx = (size_t)(bm + wm * 128 + mi * 16 + lg * 4 + r) * N +
                     bn + wn * 64 + ni * 16 + l16;
        if (BF16OUT) ((u16*)Cp)[idx] = f2bf(acc[mi][ni][r]);
        else         ((float*)Cp)[idx] = acc[mi][ni][r];
      }
}

// ---------------- 8-phase-style 256x128 GEMM (gemm2, fp32 out) ----------------
#define COMPUTE_MB(q)                                                                \
  {                                                                                  \
    bf16x8 af[2];                                                                    \
    _Pragma("unroll")                                                                \
    for (int kk = 0; kk < 2; ++kk)                                                   \
      af[kk] = load_frag(&lds2[buf][(wm * 64 + (q) * 16 + l16) * 64 +                \
                                    ((kk * 4 + lg) ^ (l16 & 7)) * 8]);               \
    __builtin_amdgcn_s_setprio(1);                                                   \
    _Pragma("unroll")                                                                \
    for (int ni = 0; ni < 4; ++ni)                                                   \
      _Pragma("unroll")                                                              \
      for (int kk = 0; kk < 2; ++kk)                                                 \
        acc[(q)][ni] = __builtin_amdgcn_mfma_f32_16x16x32_bf16(                      \
            af[kk], bper[ni][kk], acc[(q)][ni], 0, 0, 0);                            \
    __builtin_amdgcn_s_setprio(0);                                                   \
  }

__global__ __launch_bounds__(512, 2) void gemm8p_n128_kernel(const u16* __restrict__ A,
                                                             const u16* __restrict__ BT,
                                                             float* __restrict__ C,
                                                             int M, int N, int K, int gx) {
  __shared__ u16 lds2[2][24576];   // [buf][A 256x64 | B 128x64] = 96 KiB
  const int tid = threadIdx.x;
  const int wave = tid >> 6, lane = tid & 63;
  const int l16 = lane & 15, lg = lane >> 4;
  const int wm = wave >> 1, wn = wave & 1;
  const int rloc = lane >> 3;
  const int sOff = ((lane & 7) ^ rloc) * 8;
  const int nwg = gridDim.x;
  const int swz = (blockIdx.x & 7) * (nwg >> 3) + (blockIdx.x >> 3);
  const int bm = (swz / gx) * 256, bn = (swz % gx) * 128;

  f32x4 acc[4][4] = {};

  auto stageA = [&](int dstbuf, int h, int kk0) {
#pragma unroll
    for (int j = 0; j < 2; ++j) {
      int c = j * 8 + wave;
      async16(&lds2[dstbuf][h * 8192 + c * 512],
              A + (size_t)(bm + h * 128 + c * 8 + rloc) * K + kk0 + sOff);
    }
  };
  auto stageB = [&](int dstbuf, int kk0) {
#pragma unroll
    for (int j = 0; j < 2; ++j) {
      int c = j * 8 + wave;
      async16(&lds2[dstbuf][16384 + c * 512],
              BT + (size_t)(bn + c * 8 + rloc) * K + kk0 + sOff);
    }
  };

  stageA(0, 0, 0);
  stageA(0, 1, 0);
  stageB(0, 0);

  const int NT = K >> 6;
  for (int kt = 0; kt < NT; ++kt) {
    const int buf = kt & 1, nbuf = buf ^ 1;
    const int k0n = (kt + 1) << 6;
    const bool pf = (kt + 1 < NT);
    bf16x8 bper[4][2];

    if (pf) {
      stageA(nbuf, 0, k0n);
      asm volatile("s_waitcnt vmcnt(2)" ::: "memory");
    } else {
      asm volatile("s_waitcnt vmcnt(0)" ::: "memory");
    }
    __builtin_amdgcn_s_barrier();
    __builtin_amdgcn_sched_barrier(0);
#pragma unroll
    for (int ni = 0; ni < 4; ++ni)
#pragma unroll
      for (int kk = 0; kk < 2; ++kk)
        bper[ni][kk] = load_frag(&lds2[buf][16384 +
            (wn * 64 + ni * 16 + l16) * 64 + ((kk * 4 + lg) ^ (l16 & 7)) * 8]);
    COMPUTE_MB(0)
    if (pf) stageA(nbuf, 1, k0n);
    __builtin_amdgcn_s_barrier();
    __builtin_amdgcn_sched_barrier(0);
    COMPUTE_MB(1)
    if (pf) stageB(nbuf, k0n);
    __builtin_amdgcn_s_barrier();
    __builtin_amdgcn_sched_barrier(0);
    COMPUTE_MB(2)
    __builtin_amdgcn_s_barrier();
    __builtin_amdgcn_sched_barrier(0);
    COMPUTE_MB(3)
    __builtin_amdgcn_s_barrier();
  }

#pragma unroll
  for (int mb = 0; mb < 4; ++mb)
#pragma unroll
    for (int ni = 0; ni < 4; ++ni)
#pragma unroll
      for (int r = 0; r < 4; ++r)
        C[(size_t)(bm + wm * 64 + mb * 16 + lg * 4 + r) * N +
          bn + wn * 64 + ni * 16 + l16] = acc[mb][ni][r];
}

// ------------- rv: RoPE-K pack + V transpose in one launch -------------
__global__ __launch_bounds__(256) void rv_kernel(const u16* __restrict__ qkv,
                                                 const float* __restrict__ fc,
                                                 const float* __restrict__ fs,
                                                 u16* __restrict__ Kb,
                                                 u16* __restrict__ vt) {
  __shared__ u16 t[32][33];
  int bid = blockIdx.x;
  if (bid < 4096) {              // ---- rope K branch ----
    int kh = bid >> 10;
    int gi = (bid & 1023) * 256 + (int)threadIdx.x;   // (b*SEQ+s)*64 + i
    int i = gi & 63;
    int tt = gi >> 6;            // b*SEQ + s
    int s = tt & (SEQ - 1), b = tt >> 11;
    float c = fc[s * 64 + i], sn = fs[s * 64 + i];
    uint32_t pr = *reinterpret_cast<const uint32_t*>(&qkv[(size_t)tt * NQKV + NH * HD + kh * HD + 2 * i]);
    float tr = bf2f((u16)(pr & 0xffff)), ti = bf2f((u16)(pr >> 16));
    uint32_t w = (uint32_t)f2bf(tr * c - ti * sn) |
                 ((uint32_t)f2bf(tr * sn + ti * c) << 16);
    *reinterpret_cast<uint32_t*>(&Kb[((size_t)(b * NKV + kh) * SEQ + s) * HD + 2 * i]) = w;
    return;
  }
  int id = bid - 4096;           // 0..2047
  int bk = id >> 8;              // 0..7
  int rem = id & 255;
  int s0 = (rem >> 2) * 32;
  int d0 = (rem & 3) * 32;
  int b = bk >> 2, kh = bk & 3;
  int tx = threadIdx.x & 31, ty = threadIdx.x >> 5;   // ty 0..7
#pragma unroll
  for (int i = 0; i < 4; ++i) {
    int row = ty + i * 8;
    t[row][tx] = qkv[(size_t)(b * SEQ + s0 + row) * NQKV + NH * HD + NKV * HD + kh * HD + d0 + tx];
  }
  __syncthreads();
#pragma unroll
  for (int i = 0; i < 4; ++i) {
    int row = ty + i * 8;
    vt[((size_t)(b * NKV + kh) * HD + d0 + row) * SEQ + s0 + tx] = t[tx][row];
  }
}

// ---------------- causal flash attention (3 blocks/CU, Ps inside dead K buf) ---
// Round-17 structure but Ps (16x40-padded per wave, 5120 B) lives INSIDE
// Ks[cur], which is dead after the mid-step barrier (all QK^T reads of it
// complete before the barrier; next write into it is step kt+1's staging,
// fenced by the next top barrier). LDS = 48 KB -> 3 blocks/CU with the
// conflict-free padded Ps layout. All P writes moved after the mid barrier.
__global__ __launch_bounds__(256) void attn_kernel(const u16* __restrict__ qkv,
                                                   const float* __restrict__ fc,
                                                   const float* __restrict__ fs,
                                                   const u16* __restrict__ Kc,
                                                   const u16* __restrict__ VT,
                                                   u16* __restrict__ AO) {
  __shared__ u16 Ks[2][64 * 128];   // 32K, [key][d], swizzled, double-buffered
  __shared__ u16 Vs[128 * 64];      // 16K, [d][key], swizzled, single-buffered
  const int bid = blockIdx.x;
  const int qblk = 31 - (bid >> 5);
  const int bh = bid & 31;
  const int b = bh >> 4, h = bh & 15;
  const int kvh = h >> 2;
  const int tid = threadIdx.x, wave = tid >> 6, lane = tid & 63;
  const int l16 = lane & 15, lg = lane >> 4;
  const int qrow0 = qblk * 64 + wave * 16;
  const int rq = qrow0 + l16;     // this lane's q row

  const u16* Kbase = Kc + (size_t)(b * NKV + kvh) * SEQ * HD;
  const u16* Vbase = VT + (size_t)(b * NKV + kvh) * HD * SEQ;

  bf16x8 onesf;
#pragma unroll
  for (int j = 0; j < 8; ++j) onesf[j] = __builtin_bit_cast(__bf16, (u16)0x3F80);

  int kOff[4], vOff[4], kDst[4], vDst[4];
#pragma unroll
  for (int i = 0; i < 4; ++i) {
    int chunk = i * 4 + wave;                 // 0..15
    int krow = chunk * 4 + (lane >> 4);       // 0..63
    kOff[i] = krow * HD + ((lane & 15) ^ (krow & 15)) * 8;
    kDst[i] = chunk * 512;
    int vrow = chunk * 8 + (lane >> 3);       // 0..127
    vOff[i] = vrow * SEQ + ((lane & 7) ^ (vrow & 7)) * 8;
    vDst[i] = chunk * 512;
  }

  // ---- Q load + in-register RoPE ----
  const float qs = 0.12751689760098266f; // log2(e)/sqrt(128)
  const u16* Qrow = qkv + (size_t)(b * SEQ + rq) * NQKV + h * HD;
  const float* fcb = fc + (size_t)rq * 64;
  const float* fsb = fs + (size_t)rq * 64;
  bf16x8 qf[4];
#pragma unroll
  for (int c = 0; c < 4; ++c) {
    bf16x8 raw = load_frag(Qrow + c * 32 + lg * 8);
    float4 cc = *reinterpret_cast<const float4*>(fcb + c * 16 + lg * 4);
    float4 sv = *reinterpret_cast<const float4*>(fsb + c * 16 + lg * 4);
    bf16x8 q;
#pragma unroll
    for (int j = 0; j < 4; ++j) {
      float e = (float)raw[2 * j], od = (float)raw[2 * j + 1];
      float ce = (&cc.x)[j] * qs, se = (&sv.x)[j] * qs;
      q[2 * j]     = (__bf16)(e * ce - od * se);
      q[2 * j + 1] = (__bf16)(e * se + od * ce);
    }
    qf[c] = q;
  }

  f32x4 o[8] = {};
  f32x4 lsum = {};
  float m = -3e38f;

  // prologue: stage K[0]
#pragma unroll
  for (int i = 0; i < 4; ++i) async16(&Ks[0][kDst[i]], Kbase + kOff[i]);

  for (int kt = 0; kt <= qblk; ++kt) {
    const int cur = kt & 1;
    // top: own K[kt] (and Q) drained; barrier clears V/K-buf hazards
    asm volatile("s_waitcnt vmcnt(0)" ::: "memory");
    __builtin_amdgcn_s_barrier();
    __builtin_amdgcn_sched_barrier(0);
    // issue V[kt] (older 4), then K[kt+1] (newer 4)
    {
      const int k0 = kt * 64;
#pragma unroll
      for (int i = 0; i < 4; ++i) async16(&Vs[vDst[i]], Vbase + k0 + vOff[i]);
      if (kt < qblk) {
        const int k0n = (kt + 1) * 64;
#pragma unroll
        for (int i = 0; i < 4; ++i)
          async16(&Ks[cur ^ 1][kDst[i]], Kbase + (size_t)k0n * HD + kOff[i]);
      }
    }

    // QK^T swapped: s[cb][r] = S[key = kt*64+cb*16+lg*4+r][q = l16]
    f32x4 s[4] = {};
    __builtin_amdgcn_s_setprio(1);
#pragma unroll
    for (int cb = 0; cb < 4; ++cb) {
#pragma unroll
      for (int c = 0; c < 4; ++c) {
        bf16x8 kf = load_frag(&Ks[cur][(cb * 16 + l16) * 128 + (((c * 4 + lg) ^ l16) & 15) * 8]);
        s[cb] = __builtin_amdgcn_mfma_f32_16x16x32_bf16(kf, qf[c], s[cb], 0, 0, 0);
      }
    }
    __builtin_amdgcn_s_setprio(0);

    if (kt == qblk) { // diagonal tile: causal mask
      const int k0 = kt * 64;
#pragma unroll
      for (int cb = 0; cb < 4; ++cb) {
#pragma unroll
        for (int r = 0; r < 4; ++r) {
          int key = k0 + cb * 16 + lg * 4 + r;
          if (key > rq) s[cb][r] = -1e30f;
        }
      }
    }

    // per-lane tile max (q = l16) — consumes s => all Ks[cur] reads done here
    float v0 = fmaxf(fmaxf(fmaxf(s[0][0], s[0][1]), fmaxf(s[0][2], s[0][3])),
                     fmaxf(fmaxf(s[1][0], s[1][1]), fmaxf(s[1][2], s[1][3])));
    v0 = fmaxf(v0, fmaxf(fmaxf(fmaxf(s[2][0], s[2][1]), fmaxf(s[2][2], s[2][3])),
                         fmaxf(fmaxf(s[3][0], s[3][1]), fmaxf(s[3][2], s[3][3]))));
    v0 = fmaxf(v0, __shfl_xor(v0, 16));
    v0 = fmaxf(v0, __shfl_xor(v0, 32));

    bool need = v0 > m + 8.f;
    if (__any(need)) {
      float newm = fmaxf(m, v0);
      float sc = exp2f(m - newm);
      m = newm;
      float scR[4];
#pragma unroll
      for (int r = 0; r < 4; ++r) scR[r] = __shfl(sc, lg * 4 + r);
#pragma unroll
      for (int r = 0; r < 4; ++r) {
        lsum[r] *= scR[r];
#pragma unroll
        for (int db = 0; db < 8; ++db) o[db][r] *= scR[r];
      }
    }

    // mid: own V[kt] resident (K prefetch's 4 newer loads stay in flight);
    // after this barrier Ks[cur] is dead for all waves -> Ps lives in it
    if (kt < qblk) { asm volatile("s_waitcnt vmcnt(4)" ::: "memory"); }
    else           { asm volatile("s_waitcnt vmcnt(0)" ::: "memory"); }
    __builtin_amdgcn_s_barrier();
    __builtin_amdgcn_sched_barrier(0);

    u16* Ps = &Ks[cur][wave * 1280];   // 16 rows x 40 u16 (padded, conflict-free)

    // exp2 + write Ps half0 (keys 0..31: cb=0,1)
#pragma unroll
    for (int cb = 0; cb < 2; ++cb) {
      uint32_t lo = (uint32_t)f2bf(exp2f(s[cb][0] - m)) |
                    ((uint32_t)f2bf(exp2f(s[cb][1] - m)) << 16);
      uint32_t hi = (uint32_t)f2bf(exp2f(s[cb][2] - m)) |
                    ((uint32_t)f2bf(exp2f(s[cb][3] - m)) << 16);
      uint64_t w = (uint64_t)lo | ((uint64_t)hi << 32);
      *reinterpret_cast<uint64_t*>(&Ps[l16 * 40 + cb * 16 + lg * 4]) = w;
    }

    // PV half0 (keys 0..31, V slots c=0)
    {
      bf16x8 pf = load_frag(&Ps[l16 * 40 + lg * 8]);
      __builtin_amdgcn_s_setprio(1);
      lsum = __builtin_amdgcn_mfma_f32_16x16x32_bf16(pf, onesf, lsum, 0, 0, 0);
#pragma unroll
      for (int db = 0; db < 8; ++db) {
        bf16x8 vf = load_frag(&Vs[(db * 16 + l16) * 64 + ((lg) ^ (l16 & 7)) * 8]);
        o[db] = __builtin_amdgcn_mfma_f32_16x16x32_bf16(pf, vf, o[db], 0, 0, 0);
      }
      __builtin_amdgcn_s_setprio(0);
    }

    // exp2 + write Ps half1 (keys 32..63: cb=2,3) — same-wave DS is in-order
#pragma unroll
    for (int cb = 2; cb < 4; ++cb) {
      uint32_t lo = (uint32_t)f2bf(exp2f(s[cb][0] - m)) |
                    ((uint32_t)f2bf(exp2f(s[cb][1] - m)) << 16);
      uint32_t hi = (uint32_t)f2bf(exp2f(s[cb][2] - m)) |
                    ((uint32_t)f2bf(exp2f(s[cb][3] - m)) << 16);
      uint64_t w = (uint64_t)lo | ((uint64_t)hi << 32);
      *reinterpret_cast<uint64_t*>(&Ps[l16 * 40 + (cb - 2) * 16 + lg * 4]) = w;
    }

    // PV half1 (keys 32..63, V slots c=1)
    {
      bf16x8 pf = load_frag(&Ps[l16 * 40 + lg * 8]);
      __builtin_amdgcn_s_setprio(1);
      lsum = __builtin_amdgcn_mfma_f32_16x16x32_bf16(pf, onesf, lsum, 0, 0, 0);
#pragma unroll
      for (int db = 0; db < 8; ++db) {
        bf16x8 vf = load_frag(&Vs[(db * 16 + l16) * 64 + ((4 + lg) ^ (l16 & 7)) * 8]);
        o[db] = __builtin_amdgcn_mfma_f32_16x16x32_bf16(pf, vf, o[db], 0, 0, 0);
      }
      __builtin_amdgcn_s_setprio(0);
    }
  }

#pragma unroll
  for (int r = 0; r < 4; ++r) {
    float inv = 1.f / lsum[r];
    int rqo = qrow0 + lg * 4 + r;
    size_t dst = ((size_t)(b * SEQ + rqo) * NH + h) * HD;
#pragma unroll
    for (int db = 0; db < 8; ++db)
      AO[dst + db * 16 + l16] = f2bf(o[db][r] * inv);
  }
}

extern "C" void kernel_launch(void* const* d_in, const int* in_sizes, int n_in,
                              void* d_out, int out_size, void* d_ws, size_t ws_size,
                              hipStream_t stream) {
  (void)in_sizes; (void)n_in; (void)out_size; (void)ws_size;
  const float* x  = (const float*)d_in[0];
  const float* fc = (const float*)d_in[1];
  const float* fs = (const float*)d_in[2];
  const float* wq = (const float*)d_in[3];
  const float* wk = (const float*)d_in[4];
  const float* wv = (const float*)d_in[5];
  const float* wo = (const float*)d_in[6];
  float* out = (float*)d_out;

  char* ws = (char*)d_ws;
  u16*  xb    = (u16*)(ws);                      // 16,777,216
  u16*  wtqkv = (u16*)(ws + 16777216);           // 12,582,912
  u16*  wto   = (u16*)(ws + 29360128);           //  8,388,608
  u16*  qkv   = (u16*)(ws + 37748736);           // 25,165,824 (bf16)
  u16*  Kb    = (u16*)(ws + 62914560);           //  4,194,304
  u16*  VTb   = (u16*)(ws + 67108864);           //  4,194,304
  u16*  AOb   = (u16*)(ws + 71303168);           // 16,777,216

  prep_kernel<<<dim3(32, 336), dim3(256), 0, stream>>>(x, wq, wk, wv, wo, xb, wtqkv, wto);

  gemm8p_kernel<true><<<dim3(192), dim3(512), 0, stream>>>(xb, wtqkv, qkv, MROWS, NQKV, DIMSZ, 12);

  rv_kernel<<<dim3(6144), dim3(256), 0, stream>>>(qkv, fc, fs, Kb, VTb);

  attn_kernel<<<dim3(1024), dim3(256), 0, stream>>>(qkv, fc, fs, Kb, VTb, AOb);

  gemm8p_n128_kernel<<<dim3(256), dim3(512), 0, stream>>>(AOb, wto, out, MROWS, DIMSZ, DIMSZ, 16);
}